// Round 10
// baseline (42.614 us; speedup 1.0000x reference)
//
#include <hip/hip_runtime.h>
#include <hip/hip_bf16.h>
#include <float.h>
#include <math.h>

#define BB 64
#define T1 33
#define TT 32
#define II 197
#define CC 512
#define TEMP 0.07f

typedef float f32x4 __attribute__((ext_vector_type(4)));
typedef int i32x4 __attribute__((ext_vector_type(4)));
typedef int i32x8 __attribute__((ext_vector_type(8)));
typedef unsigned short u16x8 __attribute__((ext_vector_type(8)));

__device__ __forceinline__ unsigned short f32_to_bf16(float f) {
  unsigned int u = __float_as_uint(f);
  unsigned int r = u + 0x7FFFu + ((u >> 16) & 1u);  // RNE
  return (unsigned short)(r >> 16);
}
__device__ __forceinline__ float b2f(unsigned short u) {
  return __uint_as_float((unsigned int)u << 16);
}

// ---- workspace layout (bytes) ----
// Frag records for mfma_scale_f32_16x16x128_f8f6f4 (fp8): per frag per kstep,
// 2048 B = [half h 0..1][lane 0..63][16 B]; element (row/col = lane&15,
// k = ks*128 + (lane>>4)*32 + h*16 + j).
// tl8: [xc8 8][ks 4][fa 16] records  (1 MB)   A: text rows r=fa*16+(lane&15)
// ve8: [y 64][ks 4][fb 16] records  (8 MB)   B: cols  i=fb*16+(lane&15); fb<=12 written
// tti: [64 x][64 y] f32
#define TL_OFF  0
#define VE_OFF  (1 << 20)                  // 1 MB
#define TTI_OFF ((1 << 20) + (8 << 20))    // 9 MB
#define KS_STRIDE   32768                  // 16 frags * 2048
#define GRP_STRIDE  131072                 // 4 ks * KS_STRIDE

// grid (64, 8): hz 0..3 = video c-chunks (= ksteps), hz 4..7 = text c-chunks.
// 512 threads, 2 blocks/CU (62 KB LDS: cache stores bf16, squares still
// computed from f32 pre-rounding). Pass 2 builds fp8 records from the LDS
// cache (inputs read from HBM exactly once, coalesced).
__global__ __launch_bounds__(512, 4) void norm_all_kernel(const float* __restrict__ text,
                                                          const float* __restrict__ video,
                                                          unsigned char* __restrict__ tl8,
                                                          unsigned char* __restrict__ ve8) {
  int b = blockIdx.x, hz = blockIdx.y, tid = threadIdx.x;
  bool isV = hz < 4;
  int h2 = isV ? hz : hz - 4;                  // kstep
  const float* src = isV ? (video + (size_t)b * II * CC) : (text + (size_t)b * T1 * CC);
  int n = isV ? II : T1;

  __shared__ unsigned short cache[II][136];  // 53.6 KB bf16 rows x 128-chunk (pad 8)
  __shared__ float red[16][128];             // 8 KB
  __shared__ float rn[128];

  // pass 1: coalesced chunk read -> bf16 LDS cache + f32 sum of squares
  {
    int c4 = tid & 31, rg = tid >> 5;          // rg 0..15
    const float* p = src + h2 * 128 + c4 * 4;
    float4 s = {0.f, 0.f, 0.f, 0.f};
    for (int i = rg; i < n; i += 16) {
      float4 v = *(const float4*)(p + (size_t)i * CC);
      s.x += v.x * v.x; s.y += v.y * v.y; s.z += v.z * v.z; s.w += v.w * v.w;
      unsigned int o0 = f32_to_bf16(v.x) | ((unsigned int)f32_to_bf16(v.y) << 16);
      unsigned int o1 = f32_to_bf16(v.z) | ((unsigned int)f32_to_bf16(v.w) << 16);
      *(uint2*)&cache[i][c4 * 4] = make_uint2(o0, o1);
    }
    *(float4*)&red[rg][c4 * 4] = s;
  }
  __syncthreads();
  if (tid < 128) {
    float s = 0.f;
#pragma unroll
    for (int g = 0; g < 16; ++g) s += red[g][tid];
    rn[tid] = 1.0f / sqrtf(s);
  }
  __syncthreads();

  // pass 2: build 16-B record slices from the bf16 cache, fp8 e4m3.
  // slice (frag f, half h, lane l): row/col = f*16+(l&15),
  // chunk-local channels = (l>>4)*32 + h*16 + {0..15}
  if (isV) {
    for (int S = tid; S < 13 * 128; S += 512) {
      int fb = S >> 7, h = (S >> 6) & 1, lane = S & 63;
      int i = fb * 16 + (lane & 15);
      int kloc = ((lane >> 4) & 3) * 32 + h * 16;
      u16x8 v0 = {0, 0, 0, 0, 0, 0, 0, 0}, v1 = {0, 0, 0, 0, 0, 0, 0, 0};
      if (i < II) {
        v0 = *(const u16x8*)&cache[i][kloc];
        v1 = *(const u16x8*)&cache[i][kloc + 8];
      }
      float c[16];
#pragma unroll
      for (int j = 0; j < 8; ++j) { c[j] = b2f(v0[j]); c[8 + j] = b2f(v1[j]); }
      unsigned int wd[4];
#pragma unroll
      for (int q = 0; q < 4; ++q) {
        f32x4 r = *(const f32x4*)&rn[kloc + q * 4];
        int wv = __builtin_amdgcn_cvt_pk_fp8_f32(c[q * 4] * r[0], c[q * 4 + 1] * r[1], 0, 0);
        wv = __builtin_amdgcn_cvt_pk_fp8_f32(c[q * 4 + 2] * r[2], c[q * 4 + 3] * r[3], wv, 1);
        wd[q] = (unsigned int)wv;
      }
      unsigned char* dst = ve8 + (size_t)b * GRP_STRIDE + h2 * KS_STRIDE +
                           fb * 2048 + h * 1024 + lane * 16;
      *(uint4*)dst = make_uint4(wd[0], wd[1], wd[2], wd[3]);
    }
  } else if (tid < 256) {
    // 2 fa_local x 2 h x 64 lane = 256 slices
    int fa_local = tid >> 7, h = (tid >> 6) & 1, lane = tid & 63;
    int t = fa_local * 16 + (lane & 15);          // 0..31
    int kloc = ((lane >> 4) & 3) * 32 + h * 16;
    u16x8 v0 = *(const u16x8*)&cache[1 + t][kloc];
    u16x8 v1 = *(const u16x8*)&cache[1 + t][kloc + 8];
    float c[16];
#pragma unroll
    for (int j = 0; j < 8; ++j) { c[j] = b2f(v0[j]); c[8 + j] = b2f(v1[j]); }
    unsigned int wd[4];
#pragma unroll
    for (int q = 0; q < 4; ++q) {
      f32x4 r = *(const f32x4*)&rn[kloc + q * 4];
      int wv = __builtin_amdgcn_cvt_pk_fp8_f32(c[q * 4] * r[0], c[q * 4 + 1] * r[1], 0, 0);
      wv = __builtin_amdgcn_cvt_pk_fp8_f32(c[q * 4 + 2] * r[2], c[q * 4 + 3] * r[3], wv, 1);
      wd[q] = (unsigned int)wv;
    }
    int fa = (b & 7) * 2 + fa_local;
    unsigned char* dst = tl8 + (size_t)(b >> 3) * GRP_STRIDE + h2 * KS_STRIDE +
                         fa * 2048 + h * 1024 + lane * 16;
    *(uint4*)dst = make_uint4(wd[0], wd[1], wd[2], wd[3]);
  }
}

// ROUND-10 sim: zero-LDS direct-to-register (round 9) + 1-kstep software
// pipeline. Named ping-pong registers (cA*/nA*, cB*/nB* -- all compile-time,
// no runtime-indexed arrays), prefetching next kstep's A frags + first B frag
// while the current kstep's MFMAs run; remaining B frags load inside the
// compute phase under MFMA cover. asm("" ::: "memory") after each COMP caps
// the in-flight window at <=2 ksteps so the compiler cannot hoist all loads
// and spill (rounds 5/7 lesson). Peak live ~100 regs < (512,4)'s 128 cap.
// 2048 blocks x 512 threads, 64 rows x 208 cols, 4 ksteps of 128.
__global__ __launch_bounds__(512, 4) void sim_kernel(const unsigned char* __restrict__ tl8,
                                                     const unsigned char* __restrict__ ve8,
                                                     const int* __restrict__ mask,
                                                     float* __restrict__ tti) {
  int L = blockIdx.x;
  int xcd = L & 7;
  int idx = L >> 3;              // 0..255
  int y = xcd * 8 + (idx & 7);   // each XCD owns 8 consecutive y's
  int xcb = idx >> 3;            // 0..31 : 2 batch-x per block (64 rows)

  int tid = threadIdx.x;
  int w = tid >> 6, lane = tid & 63;
  int wm = w & 1;                // rows wm*32..+32 (2 frags)
  int wn = w >> 1;               // col frags wn, wn+4, wn+8 (+12 if wn==0)

  __shared__ float smax[4 * 64]; // [wn][row] 1 KB

  const unsigned char* Ab = tl8 + (size_t)(xcb >> 2) * GRP_STRIDE +
                            (size_t)(xcb & 3) * 4 * 2048 +
                            (size_t)(wm * 2) * 2048 + lane * 16;
  const unsigned char* Bb = ve8 + (size_t)y * GRP_STRIDE +
                            (size_t)wn * 2048 + lane * 16;

  f32x4 acc[2][4] = {};

#define MFMA_(aop, bop, c) __builtin_amdgcn_mfma_scale_f32_16x16x128_f8f6f4( \
      aop, bop, c, 0, 0, 0, 0x7F7F7F7F, 0, 0x7F7F7F7F)
#define SHUF_(a, b) __builtin_shufflevector(a, b, 0, 1, 2, 3, 4, 5, 6, 7)

#define LDA_(d0, d1, d2, d3, s_) do {                                         \
    const unsigned char* p_ = Ab + (size_t)(s_) * KS_STRIDE;                  \
    d0 = *(const i32x4*)p_;          d1 = *(const i32x4*)(p_ + 1024);         \
    d2 = *(const i32x4*)(p_ + 2048); d3 = *(const i32x4*)(p_ + 3072);         \
  } while (0)
#define LDB_(d0, d1, s_) do {                                                 \
    const unsigned char* p_ = Bb + (size_t)(s_) * KS_STRIDE;                  \
    d0 = *(const i32x4*)p_; d1 = *(const i32x4*)(p_ + 1024);                  \
  } while (0)

  // COMP: nb=0 from prefetched (b0,b1); nb=1,2 (and 3 for wn==0) loaded
  // in-phase -- earlier MFMAs cover their latency.
#define COMP_(s_, a0, a1, a2, a3, b0, b1) do {                                \
    i32x8 aop0_ = SHUF_(a0, a1), aop1_ = SHUF_(a2, a3);                       \
    i32x8 bop_ = SHUF_(b0, b1);                                               \
    acc[0][0] = MFMA_(aop0_, bop_, acc[0][0]);                                \
    acc[1][0] = MFMA_(aop1_, bop_, acc[1][0]);                                \
    {                                                                         \
      const unsigned char* p_ = Bb + (size_t)(s_) * KS_STRIDE + 8192;         \
      i32x4 t0_ = *(const i32x4*)p_, t1_ = *(const i32x4*)(p_ + 1024);        \
      bop_ = SHUF_(t0_, t1_);                                                 \
      acc[0][1] = MFMA_(aop0_, bop_, acc[0][1]);                              \
      acc[1][1] = MFMA_(aop1_, bop_, acc[1][1]);                              \
    }                                                                         \
    {                                                                         \
      const unsigned char* p_ = Bb + (size_t)(s_) * KS_STRIDE + 16384;        \
      i32x4 t0_ = *(const i32x4*)p_, t1_ = *(const i32x4*)(p_ + 1024);        \
      bop_ = SHUF_(t0_, t1_);                                                 \
      acc[0][2] = MFMA_(aop0_, bop_, acc[0][2]);                              \
      acc[1][2] = MFMA_(aop1_, bop_, acc[1][2]);                              \
    }                                                                         \
    if (wn == 0) {                                                            \
      const unsigned char* p_ = Bb + (size_t)(s_) * KS_STRIDE + 24576;        \
      i32x4 t0_ = *(const i32x4*)p_, t1_ = *(const i32x4*)(p_ + 1024);        \
      bop_ = SHUF_(t0_, t1_);                                                 \
      acc[0][3] = MFMA_(aop0_, bop_, acc[0][3]);                              \
      acc[1][3] = MFMA_(aop1_, bop_, acc[1][3]);                              \
    }                                                                         \
  } while (0)

  i32x4 cA0, cA1, cA2, cA3, nA0, nA1, nA2, nA3;
  i32x4 cB0, cB1, nB0, nB1;

  // prologue: kstep0 operands + kstep1 prefetch in flight
  LDA_(cA0, cA1, cA2, cA3, 0); LDB_(cB0, cB1, 0);
  LDA_(nA0, nA1, nA2, nA3, 1); LDB_(nB0, nB1, 1);

  COMP_(0, cA0, cA1, cA2, cA3, cB0, cB1);
  asm volatile("" ::: "memory");
  LDA_(cA0, cA1, cA2, cA3, 2); LDB_(cB0, cB1, 2);
  COMP_(1, nA0, nA1, nA2, nA3, nB0, nB1);
  asm volatile("" ::: "memory");
  LDA_(nA0, nA1, nA2, nA3, 3); LDB_(nB0, nB1, 3);
  COMP_(2, cA0, cA1, cA2, cA3, cB0, cB1);
  asm volatile("" ::: "memory");
  COMP_(3, nA0, nA1, nA2, nA3, nB0, nB1);

#undef LDA_
#undef LDB_
#undef COMP_
#undef MFMA_
#undef SHUF_

  // ---- fused epilogue: max over i (i<197), masked mean over t -> tti ----
  int col = lane & 15, gq = lane >> 4;
  int nfrag = (wn == 0) ? 4 : 3;
  bool valid[4];
#pragma unroll
  for (int nb = 0; nb < 4; ++nb) {
    int fb = wn + 4 * nb;
    valid[nb] = (nb < nfrag) && (fb * 16 + col < II);
  }

  float mx[2][4];
#pragma unroll
  for (int ma = 0; ma < 2; ++ma)
#pragma unroll
    for (int reg = 0; reg < 4; ++reg) {
      float m = -FLT_MAX;
#pragma unroll
      for (int nb = 0; nb < 4; ++nb)
        if (valid[nb]) m = fmaxf(m, acc[ma][nb][reg]);
      mx[ma][reg] = m;
    }
#pragma unroll
  for (int st = 1; st <= 8; st <<= 1)
#pragma unroll
    for (int ma = 0; ma < 2; ++ma)
#pragma unroll
      for (int reg = 0; reg < 4; ++reg)
        mx[ma][reg] = fmaxf(mx[ma][reg], __shfl_xor(mx[ma][reg], st));

  if (col == 0) {
#pragma unroll
    for (int ma = 0; ma < 2; ++ma)
#pragma unroll
      for (int reg = 0; reg < 4; ++reg)
        smax[wn * 64 + wm * 32 + ma * 16 + gq * 4 + reg] = mx[ma][reg];
  }
  __syncthreads();

  if (tid < 64) {
    int r = tid;                       // row = x_local*32 + t (x_local 0..1)
    float m = fmaxf(fmaxf(smax[r], smax[64 + r]),
                    fmaxf(smax[128 + r], smax[192 + r]));
    int x = xcb * 2 + (r >> 5), tt = r & 31;
    int mk = mask[x * T1 + 1 + tt];
    float num = mk ? m * TEMP : 0.f;
    float cnt = mk ? 1.f : 0.f;
#pragma unroll
    for (int st = 1; st < 32; st <<= 1) {
      num += __shfl_xor(num, st);
      cnt += __shfl_xor(cnt, st);
    }
    if (tt == 0) tti[x * 64 + y] = num / fmaxf(cnt, 1e-6f);
  }
}

// 1 block x 1024 threads: 16 threads per row x, each sums 4 y's.
__global__ void loss_kernel(const float* __restrict__ tti, float* __restrict__ out) {
  __shared__ float lxs[64];
  int tid = threadIdx.x;
  int x = tid >> 4, q = tid & 15;
  float4 v = *(const float4*)&tti[x * 64 + q * 4];
  float den = expf(v.x) + expf(v.y) + expf(v.z) + expf(v.w);
#pragma unroll
  for (int st = 1; st < 16; st <<= 1) den += __shfl_xor(den, st);
  if (q == 0) {
    float pos = expf(tti[x * 64 + x]);
    lxs[x] = -logf(pos / den + 1e-20f);
  }
  __syncthreads();
  if (tid < 64) {
    float lx = lxs[tid];
#pragma unroll
    for (int s = 1; s < 64; s <<= 1) lx += __shfl_xor(lx, s);
    if (tid == 0) out[0] = lx * (1.0f / 64.0f);
  }
}

extern "C" void kernel_launch(void* const* d_in, const int* in_sizes, int n_in,
                              void* d_out, int out_size, void* d_ws, size_t ws_size,
                              hipStream_t stream) {
  const float* text = (const float*)d_in[0];   // [64][33][512] f32
  const float* video = (const float*)d_in[1];  // [64][197][512] f32
  const int* mask = (const int*)d_in[2];       // [64][33] i32
  float* out = (float*)d_out;

  char* ws = (char*)d_ws;
  unsigned char* tl8 = (unsigned char*)(ws + TL_OFF);
  unsigned char* ve8 = (unsigned char*)(ws + VE_OFF);
  float* tti = (float*)(ws + TTI_OFF);

  hipLaunchKernelGGL(norm_all_kernel, dim3(BB, 8), dim3(512), 0, stream, text, video, tl8, ve8);
  hipLaunchKernelGGL(sim_kernel, dim3(2048), dim3(512), 0, stream, tl8, ve8, mask, tti);
  hipLaunchKernelGGL(loss_kernel, dim3(1), dim3(1024), 0, stream, tti, out);
}